// Round 8
// baseline (342.408 us; speedup 1.0000x reference)
//
#include <hip/hip_runtime.h>
#include <cstdint>
#include <cstddef>

#define NNODES 50000
#define NEDGES 800000
#define INDIM  256
#define HD     128   // H*D
#define NH     4
#define NEG    0.2f

#define SCAN_B ((NNODES + 255) / 256)   // 196 blocks
#define NRT    ((NNODES + 15) / 16)     // 3125 -> pad to 3128 via 128-row blocks
#define NRB    ((NNODES + 127) / 128)   // 391 row-blocks (covers 50048 rows)

typedef __attribute__((ext_vector_type(8))) short   short8;   // 8 bf16 (4 VGPRs)
typedef __attribute__((ext_vector_type(8))) ushort  ushort8;
typedef __attribute__((ext_vector_type(4))) float   floatx4;

// f32 -> bf16 (round-to-nearest-even), raw bits
__device__ __forceinline__ ushort f2bf(float f) {
    unsigned u = __float_as_uint(f);
    unsigned r = u + 0x7fffu + ((u >> 16) & 1u);
    return (ushort)(r >> 16);
}
__device__ __forceinline__ float bf2f(ushort u) {
    return __uint_as_float(((unsigned)u) << 16);
}

// ============ fragment-order layouts ============
// A-fragment chunk for (row-tile rt, k-step ks, lane l): 8 bf16 =
//   h[rt*16 + (l&15)][ks*32 + (l>>4)*8 .. +8]
// stored at h_frag + ((rt*8 + ks)*64 + l)*8.  (chunk = 16 B, lane-contiguous)
// B likewise with n-tile tn: Wt_frag + ((tn*8 + ks)*64 + l)*8, n = tn*16 + (l&15).

// ================= conv_h: h f32 -> fragment-ordered bf16 =================
// one block per row-tile (16 rows x 256 k)
__global__ __launch_bounds__(256) void conv_h_kernel(
        const float* __restrict__ h, ushort* __restrict__ h_frag) {
    __shared__ float t[16][260];
    const int rt = blockIdx.x;
    const int tid = threadIdx.x;
    const int r = tid >> 4, cb = tid & 15;
    const int grow = rt * 16 + r;
    float4 v[4];
    if (grow < NNODES) {
        const float* hp = h + (size_t)grow * INDIM + cb * 16;
#pragma unroll
        for (int q = 0; q < 4; ++q) v[q] = *(const float4*)(hp + q * 4);
    } else {
#pragma unroll
        for (int q = 0; q < 4; ++q) v[q] = (float4){0.f, 0.f, 0.f, 0.f};
    }
#pragma unroll
    for (int q = 0; q < 4; ++q) {
        t[r][cb * 16 + q * 4 + 0] = v[q].x;
        t[r][cb * 16 + q * 4 + 1] = v[q].y;
        t[r][cb * 16 + q * 4 + 2] = v[q].z;
        t[r][cb * 16 + q * 4 + 3] = v[q].w;
    }
    __syncthreads();
#pragma unroll
    for (int i = 0; i < 2; ++i) {
        int c = tid + i * 256;                 // 0..511
        int ks = c >> 6, quad = (c >> 4) & 3, l15 = c & 15;
        ushort8 o;
#pragma unroll
        for (int j = 0; j < 8; ++j)
            o[j] = f2bf(t[l15][ks * 32 + quad * 8 + j]);
        *(ushort8*)(h_frag + ((size_t)rt * 512 + c) * 8) = o;
    }
}

// ================= conv_w: W -> fragment-ordered bf16 =================
// one block per n-tile (16 cols x 256 k); tn<8 -> Wsrc, else Wdst
__global__ __launch_bounds__(256) void conv_w_kernel(
        const float* __restrict__ Wsrc, const float* __restrict__ Wdst,
        ushort* __restrict__ Wt_frag) {
    __shared__ float t[256][17];
    const int tn = blockIdx.x;       // 0..15
    const int tid = threadIdx.x;     // k row
    const float* Wbase = (tn < 8) ? Wsrc : Wdst;
    const int c0 = (tn & 7) * 16;
#pragma unroll
    for (int j = 0; j < 16; ++j)
        t[tid][j] = Wbase[(size_t)tid * HD + c0 + j];
    __syncthreads();
#pragma unroll
    for (int i = 0; i < 2; ++i) {
        int c = tid + i * 256;
        int ks = c >> 6, quad = (c >> 4) & 3, l15 = c & 15;
        ushort8 o;
#pragma unroll
        for (int j = 0; j < 8; ++j)
            o[j] = f2bf(t[ks * 32 + quad * 8 + j][l15]);
        *(ushort8*)(Wt_frag + ((size_t)tn * 512 + c) * 8) = o;
    }
}

// ================= MFMA GEMM v2: barrier-free K-loop =================
// block = 128 rows x 128 cols. blockIdx.x = col-half (0: el, 1: er).
// B half (8 n-tiles, 64 KB) persists in LDS; A fragments stream from global.
// wave w: all 8 m-tiles x n-tiles {w*2, w*2+1}.
__global__ __launch_bounds__(256) void gemm_mfma_kernel(
        const ushort* __restrict__ h_frag, const ushort* __restrict__ Wt_frag,
        const float* __restrict__ bsrc, const float* __restrict__ bdst,
        ushort* __restrict__ el_bf, float* __restrict__ er) {
    __shared__ ushort Bs[4096 * 8];   // 64 KB

    const int tid  = threadIdx.x;
    const int wave = tid >> 6, lane = tid & 63;
    const int ch   = blockIdx.x;          // col-half
    const int rt0  = blockIdx.y * 8;      // base row-tile
    const int l15  = lane & 15, quad = lane >> 4;

    // stage B: 4096 chunks, 16/thread, fully coalesced
    const ushort* Bg = Wt_frag + (size_t)ch * 4096 * 8;
#pragma unroll
    for (int i = 0; i < 16; ++i) {
        int c = tid + i * 256;
        *(ushort8*)(Bs + (size_t)c * 8) = *(const ushort8*)(Bg + (size_t)c * 8);
    }
    __syncthreads();   // the only barrier

    floatx4 acc[8][2];
#pragma unroll
    for (int i = 0; i < 8; ++i) {
        acc[i][0] = (floatx4){0.f, 0.f, 0.f, 0.f};
        acc[i][1] = (floatx4){0.f, 0.f, 0.f, 0.f};
    }

#pragma unroll
    for (int ks = 0; ks < 8; ++ks) {
        short8 bf0 = *(const short8*)(Bs + ((size_t)((wave * 2 + 0) * 8 + ks) * 64 + lane) * 8);
        short8 bf1 = *(const short8*)(Bs + ((size_t)((wave * 2 + 1) * 8 + ks) * 64 + lane) * 8);
#pragma unroll
        for (int mt = 0; mt < 8; ++mt) {
            short8 af = *(const short8*)(h_frag + ((size_t)((rt0 + mt) * 8 + ks) * 64 + lane) * 8);
            acc[mt][0] = __builtin_amdgcn_mfma_f32_16x16x32_bf16(af, bf0, acc[mt][0], 0, 0, 0);
            acc[mt][1] = __builtin_amdgcn_mfma_f32_16x16x32_bf16(af, bf1, acc[mt][1], 0, 0, 0);
        }
    }

    // epilogue: C/D layout col=lane&15, row=quad*4+reg
#pragma unroll
    for (int tn = 0; tn < 2; ++tn) {
        int col = (wave * 2 + tn) * 16 + l15;   // 0..127 within half
        float bias = (ch == 0) ? bsrc[col] : bdst[col];
#pragma unroll
        for (int mt = 0; mt < 8; ++mt) {
#pragma unroll
            for (int reg = 0; reg < 4; ++reg) {
                int row = (rt0 + mt) * 16 + quad * 4 + reg;
                if (row < NNODES) {
                    float v = acc[mt][tn][reg] + bias;
                    if (ch == 0) el_bf[(size_t)row * HD + col] = f2bf(v);
                    else         er[(size_t)row * HD + col] = v;
                }
            }
        }
    }
}

// ================= CSR build =================
__global__ __launch_bounds__(256) void hist_kernel(
        const int* __restrict__ dst, int* __restrict__ cnt_work) {
    int e = blockIdx.x * blockDim.x + threadIdx.x;
    if (e < NEDGES) atomicAdd(cnt_work + dst[e], 1);
}

__global__ __launch_bounds__(256) void scan_partial_kernel(
        const int* __restrict__ cnt, int* __restrict__ partials) {
    __shared__ int lds[256];
    int i = blockIdx.x * 256 + threadIdx.x;
    lds[threadIdx.x] = (i < NNODES) ? cnt[i] : 0;
    __syncthreads();
    for (int off = 128; off > 0; off >>= 1) {
        if (threadIdx.x < off) lds[threadIdx.x] += lds[threadIdx.x + off];
        __syncthreads();
    }
    if (threadIdx.x == 0) partials[blockIdx.x] = lds[0];
}

__global__ __launch_bounds__(256) void scan_offsets_kernel(
        int* __restrict__ partials, int* __restrict__ rowptr) {
    __shared__ int lds[256];
    int t = threadIdx.x;
    int v = (t < SCAN_B) ? partials[t] : 0;
    lds[t] = v;
    __syncthreads();
    for (int off = 1; off < 256; off <<= 1) {
        int u = (t >= off) ? lds[t - off] : 0;
        __syncthreads();
        lds[t] += u;
        __syncthreads();
    }
    if (t < SCAN_B) partials[t] = lds[t] - v;      // exclusive
    if (t == 255) rowptr[NNODES] = lds[255];       // total
}

__global__ __launch_bounds__(256) void scan_final_kernel(
        int* __restrict__ cnt_work, const int* __restrict__ partials,
        int* __restrict__ rowptr) {
    __shared__ int lds[256];
    int i = blockIdx.x * 256 + threadIdx.x;
    int t = threadIdx.x;
    int v = (i < NNODES) ? cnt_work[i] : 0;
    lds[t] = v;
    __syncthreads();
    for (int off = 1; off < 256; off <<= 1) {
        int u = (t >= off) ? lds[t - off] : 0;
        __syncthreads();
        lds[t] += u;
        __syncthreads();
    }
    if (i < NNODES) {
        int start = partials[blockIdx.x] + lds[t] - v;
        rowptr[i] = start;
        cnt_work[i] = start;
    }
}

__global__ __launch_bounds__(256) void scatter_kernel(
        const int* __restrict__ src, const int* __restrict__ dst,
        int* __restrict__ cnt_work, int2* __restrict__ epair) {
    int e = blockIdx.x * blockDim.x + threadIdx.x;
    if (e >= NEDGES) return;
    int s = src[e];
    int pos = atomicAdd(cnt_work + dst[e], 1);
    epair[pos] = make_int2(e, s);
}

// ================= fused: scores + online softmax + aggregate + normalize =================
#define DEGCAP 128

__global__ __launch_bounds__(256) void node_fused_kernel(
        const ushort* __restrict__ el_bf, const float* __restrict__ er,
        const int* __restrict__ rowptr, const int2* __restrict__ epair,
        const float* __restrict__ attn,
        float* __restrict__ out_feat, float* __restrict__ out_a) {
    __shared__ float sp[4][DEGCAP * NH];   // 2 KB per wave

    const int wv = threadIdx.x >> 6;
    const int n = blockIdx.x * 4 + wv;
    if (n >= NNODES) return;
    const int lane = threadIdx.x & 63;
    const int hh = lane >> 4;
    const int lo = rowptr[n], hi = rowptr[n + 1];
    const int deg = hi - lo;
    float* spw = sp[wv];

    const float2 rv = *(const float2*)(er + (size_t)n * HD + lane * 2);
    const float a0 = attn[lane * 2], a1 = attn[lane * 2 + 1];

    float m = -3.4e38f, lsum = 0.0f, acc0 = 0.0f, acc1 = 0.0f;

#define LOADU(var, j) \
    if ((j) < deg) { int s_ = epair[lo + (j)].y; \
        var = *(const ushort2*)(el_bf + (size_t)s_ * HD + lane * 2); }

#define PROC(u, j) \
    if ((j) < deg) { \
        float evx = bf2f(u.x), evy = bf2f(u.y); \
        if ((j) + 4 < deg) { int s_ = epair[lo + (j) + 4].y; \
            u = *(const ushort2*)(el_bf + (size_t)s_ * HD + lane * 2); } \
        float x0 = evx + rv.x; x0 = x0 > 0.f ? x0 : NEG * x0; \
        float x1 = evy + rv.y; x1 = x1 > 0.f ? x1 : NEG * x1; \
        float p = x0 * a0 + x1 * a1; \
        p += __shfl_xor(p, 1, 16); \
        p += __shfl_xor(p, 2, 16); \
        p += __shfl_xor(p, 4, 16); \
        p += __shfl_xor(p, 8, 16); \
        if ((lane & 15) == 0) spw[(j) * NH + hh] = p; \
        float d_ = p - m; \
        bool up_ = (d_ >= 0.f); \
        float e_ = __expf(up_ ? -d_ : d_); \
        float sc = up_ ? e_ : 1.f; \
        float w  = up_ ? 1.f : e_; \
        if (up_) m = p; \
        lsum = lsum * sc + w; \
        acc0 = acc0 * sc + w * evx; \
        acc1 = acc1 * sc + w * evy; \
    }

    if (deg > 0 && deg <= DEGCAP) {
        ushort2 u0 = {0,0}, u1 = {0,0}, u2 = {0,0}, u3 = {0,0};
        LOADU(u0, 0) LOADU(u1, 1) LOADU(u2, 2) LOADU(u3, 3)
        for (int j0 = 0; j0 < deg; j0 += 4) {
            PROC(u0, j0)
            PROC(u1, j0 + 1)
            PROC(u2, j0 + 2)
            PROC(u3, j0 + 3)
        }
    } else if (deg > DEGCAP) {
        ushort2 u = {0,0};
        { int s_ = epair[lo].y; u = *(const ushort2*)(el_bf + (size_t)s_ * HD + lane * 2); }
        for (int i = lo; i < hi; ++i) {
            float evx = bf2f(u.x), evy = bf2f(u.y);
            if (i + 1 < hi) { int s_ = epair[i + 1].y;
                u = *(const ushort2*)(el_bf + (size_t)s_ * HD + lane * 2); }
            float x0 = evx + rv.x; x0 = x0 > 0.f ? x0 : NEG * x0;
            float x1 = evy + rv.y; x1 = x1 > 0.f ? x1 : NEG * x1;
            float p = x0 * a0 + x1 * a1;
            p += __shfl_xor(p, 1, 16);
            p += __shfl_xor(p, 2, 16);
            p += __shfl_xor(p, 4, 16);
            p += __shfl_xor(p, 8, 16);
            float mn = fmaxf(m, p);
            float sc = __expf(m - mn);
            float w  = __expf(p - mn);
            lsum = lsum * sc + w;
            acc0 = acc0 * sc + w * evx;
            acc1 = acc1 * sc + w * evy;
            m = mn;
        }
    }

    float2 o;
    if (deg == 0) { o.x = 0.0f; o.y = 0.0f; }
    else { float inv = 1.0f / lsum; o.x = acc0 * inv; o.y = acc1 * inv; }
    *(float2*)(out_feat + (size_t)n * HD + lane * 2) = o;

    if (deg == 0) return;

    float inv = 1.0f / lsum;
    if (deg <= DEGCAP) {
        float mh   = __shfl(m,   (lane & 3) << 4, 64);
        float invh = __shfl(inv, (lane & 3) << 4, 64);
        for (int j = (lane >> 2); j < deg; j += 16) {
            int e = epair[lo + j].x;
            float p = spw[j * NH + (lane & 3)];
            out_a[(size_t)e * NH + (lane & 3)] = __expf(p - mh) * invh;
        }
    } else {
        for (int i = lo; i < hi; ++i) {
            int s_ = epair[i].y;
            ushort2 u = *(const ushort2*)(el_bf + (size_t)s_ * HD + lane * 2);
            float evx = bf2f(u.x), evy = bf2f(u.y);
            float x0 = evx + rv.x; x0 = x0 > 0.f ? x0 : NEG * x0;
            float x1 = evy + rv.y; x1 = x1 > 0.f ? x1 : NEG * x1;
            float p = x0 * a0 + x1 * a1;
            p += __shfl_xor(p, 1, 16);
            p += __shfl_xor(p, 2, 16);
            p += __shfl_xor(p, 4, 16);
            p += __shfl_xor(p, 8, 16);
            if ((lane & 15) == 0) {
                int e = epair[i].x;
                out_a[(size_t)e * NH + hh] = __expf(p - m) * inv;
            }
        }
    }
#undef LOADU
#undef PROC
}

extern "C" void kernel_launch(void* const* d_in, const int* in_sizes, int n_in,
                              void* d_out, int out_size, void* d_ws, size_t ws_size,
                              hipStream_t stream) {
    const float* h    = (const float*)d_in[0];
    const int*   src  = (const int*)d_in[1];
    const int*   dst  = (const int*)d_in[2];
    const float* Wsrc = (const float*)d_in[3];
    const float* bsrc = (const float*)d_in[4];
    const float* Wdst = (const float*)d_in[5];
    const float* bdst = (const float*)d_in[6];
    const float* attn = (const float*)d_in[7];

    float* out_feat = (float*)d_out;                       // N*128
    float* out_a    = out_feat + (size_t)NNODES * HD;      // E*4

    // h_frag scratch lives in d_out (28.8 MB region, fully rewritten by
    // node_fused later): conv_h -> gemm consume it first. 25.6 MB needed.
    ushort* h_frag = (ushort*)d_out;                       // NRB*128 rows worth

    // workspace layout
    float*  er       = (float*)d_ws;                         // N*128 f32 (25.6 MB)
    ushort* Wt_frag  = (ushort*)(er + (size_t)NNODES * HD);  // 16*512*8 = 128 KB
    ushort* el_bf    = Wt_frag + 16 * 512 * 8;               // N*128 bf16 (12.8 MB)
    int2*   epair    = (int2*)(el_bf + (size_t)NNODES * HD); // E int2 (6.4 MB)
    int*    cnt_work = (int*)(epair + NEDGES);               // N
    int*    rowptr   = cnt_work + NNODES;                    // N+1
    int*    partials = rowptr + NNODES + 1;                  // SCAN_B

    hipMemsetAsync(cnt_work, 0, NNODES * sizeof(int), stream);

    conv_w_kernel<<<16, 256, 0, stream>>>(Wsrc, Wdst, Wt_frag);
    conv_h_kernel<<<NRB * 8, 256, 0, stream>>>(h, h_frag);

    dim3 ggrid(2, NRB);
    gemm_mfma_kernel<<<ggrid, 256, 0, stream>>>(h_frag, Wt_frag, bsrc, bdst, el_bf, er);

    hist_kernel<<<(NEDGES + 255) / 256, 256, 0, stream>>>(dst, cnt_work);
    scan_partial_kernel<<<SCAN_B, 256, 0, stream>>>(cnt_work, partials);
    scan_offsets_kernel<<<1, 256, 0, stream>>>(partials, rowptr);
    scan_final_kernel<<<SCAN_B, 256, 0, stream>>>(cnt_work, partials, rowptr);
    scatter_kernel<<<(NEDGES + 255) / 256, 256, 0, stream>>>(src, dst, cnt_work, epair);

    node_fused_kernel<<<(NNODES + 3) / 4, 256, 0, stream>>>(
        el_bf, er, rowptr, epair, attn, out_feat, out_a);
}